// Round 23
// baseline (130.081 us; speedup 1.0000x reference)
//
#include <hip/hip_runtime.h>
#include <hip/hip_bf16.h>

// MultiHeadAttention: B=2, S=2048, D=1024, H=16, key=head=64
// transpose_w (W->W^T bf16, Wq pre-scaled 0.125*log2e; also emits mb bf16 mask)
// proj_gemm (128x256 tile, __launch_bounds__(256,3): occupancy-corrected R16
//   retry — R16's (256,2) capped residency at 8 waves/CU and confounded the
//   tile-ratio test; LDS 49.7KB allows 3 blocks/CU, VGPR 104 fits 3 waves/SIMD.
//   Fused fp32->bf16 A-staging, T14 issue-early/write-late; z==2 epilogue
//   writes vt directly with mask-zeroing)
// attn_fwd: R14-verified (Q-tile 256, 8 waves qh x kh, A-reuse, swapped QK^T,
//   sigma-permuted K staging, in-register P, merge-by-addition epilogue)

#define SEQ 2048
#define DIM 1024
#define NPROJ 1024

typedef __bf16 bf16x8 __attribute__((ext_vector_type(8)));
typedef float floatx4 __attribute__((ext_vector_type(4)));
typedef float floatx16 __attribute__((ext_vector_type(16)));

__device__ inline unsigned short f2bf_bits(float x) {
  __hip_bfloat16 h = __float2bfloat16(x);
  return __builtin_bit_cast(unsigned short, h);
}

__device__ __forceinline__ void gload_lds16(const void* g, void* l) {
  __builtin_amdgcn_global_load_lds((const __attribute__((address_space(1))) void*)g,
                                   (__attribute__((address_space(3))) void*)l, 16, 0, 0);
}

// ---------------------------------------------------------------------------
// Kernel 1: W [1024x1024] fp32 -> W^T bf16; Wq scaled by 0.125*log2e.
// Side job (z==1, y==0, x<16): mb[b][s] = bf16(mask) for attn's rowsum MFMA.
// ---------------------------------------------------------------------------
__global__ __launch_bounds__(256) void transpose_w(
    const float* __restrict__ Wq, const float* __restrict__ Wk, const float* __restrict__ Wv,
    const int* __restrict__ vmask,
    unsigned short* __restrict__ WqT, unsigned short* __restrict__ WkT, unsigned short* __restrict__ WvT,
    unsigned short* __restrict__ mb)
{
  if (blockIdx.z == 1 && blockIdx.y == 0 && blockIdx.x < 16) {
    int i = blockIdx.x * 256 + threadIdx.x;
    mb[i] = vmask[i] ? 0x3F80 : 0;   // bf16 1.0 or 0.0
  }
  const float* W = blockIdx.z == 0 ? Wq : (blockIdx.z == 1 ? Wk : Wv);
  unsigned short* WT = blockIdx.z == 0 ? WqT : (blockIdx.z == 1 ? WkT : WvT);
  const float sc = (blockIdx.z == 0) ? 0.1803368801f : 1.0f;
  __shared__ float tile[64][65];
  const int k0 = blockIdx.x * 64;
  const int n0 = blockIdx.y * 64;
  const int t = threadIdx.x;
  #pragma unroll
  for (int it = 0; it < 4; ++it) {
    int idx = t + (it << 8);
    int r = idx >> 4, c4 = (idx & 15) << 2;
    float4 v = *reinterpret_cast<const float4*>(&W[(k0 + r) * DIM + n0 + c4]);
    tile[r][c4 + 0] = v.x; tile[r][c4 + 1] = v.y;
    tile[r][c4 + 2] = v.z; tile[r][c4 + 3] = v.w;
  }
  __syncthreads();
  #pragma unroll
  for (int it = 0; it < 4; ++it) {
    int idx = t + (it << 8);
    int r = idx >> 4, c4 = (idx & 15) << 2;
    ushort4 o;
    o.x = f2bf_bits(tile[c4 + 0][r] * sc);
    o.y = f2bf_bits(tile[c4 + 1][r] * sc);
    o.z = f2bf_bits(tile[c4 + 2][r] * sc);
    o.w = f2bf_bits(tile[c4 + 3][r] * sc);
    *reinterpret_cast<ushort4*>(&WT[(n0 + r) * DIM + k0 + c4]) = o;
  }
}

// ---------------------------------------------------------------------------
// Kernel 2: Y = bf16( X @ W ), X = q/k/v fp32 [4096x1024] read DIRECTLY.
// 128x256 tile, BK=32, double-buffered, 49.7 KB LDS, 3 blocks/CU.
// 4 waves: wm 2 x wn 2, per-wave output 64x128 (acc[4][8], 32 MFMA/step).
// T14 split A-staging (issue-early / write-late), B via global_load_lds.
// z==0/1: Y = qw/kw row-major. z==2: epilogue writes vt[(b16+h)64+d][s]
// directly (mask-zeroed rows via LDS-staged vmask slice).
// ---------------------------------------------------------------------------
__global__ __launch_bounds__(256, 3) void proj_gemm(
    const float* __restrict__ xq, const float* __restrict__ xk, const float* __restrict__ xv,
    const unsigned short* __restrict__ WqT, const unsigned short* __restrict__ WkT,
    const unsigned short* __restrict__ WvT, const int* __restrict__ vmask,
    unsigned short* __restrict__ qw, unsigned short* __restrict__ kw, unsigned short* __restrict__ vt)
{
  const float* X = blockIdx.z == 0 ? xq : (blockIdx.z == 1 ? xk : xv);
  const unsigned short* WT = blockIdx.z == 0 ? WqT : (blockIdx.z == 1 ? WkT : WvT);

  __shared__ unsigned short Al[2][128 * 32];  // [m][k] bf16, 64B rows, swizzled chunks
  __shared__ unsigned short Bl[2][256 * 32];  // [n][k]
  __shared__ int vml[128];                    // z==2: mask slice for rows m0..m0+127

  const int m0 = blockIdx.x * 128, n0 = blockIdx.y * 256;
  const int t = threadIdx.x;
  const int lane = t & 63;
  const int wid = t >> 6;
  const int wm = (wid >> 1) << 6, wn = (wid & 1) << 7;
  const int qd = lane >> 4, ln = lane & 15;

  if (blockIdx.z == 2 && t < 128) vml[t] = vmask[m0 + t];

  float4 ra[2], rb[2];   // in-flight A chunks (one tile resident at a time)

  auto loadA = [&](int ks) {   // issue only — no wait
    #pragma unroll
    for (int i = 0; i < 2; ++i) {
      int p = t + (i << 8);
      int r = p >> 2, c = p & 3;
      int f = (r + (r >> 2)) & 3;
      const float* ga = X + (size_t)(m0 + r) * 1024 + ks * 32 + ((c ^ f) << 3);
      ra[i] = *reinterpret_cast<const float4*>(ga);
      rb[i] = *reinterpret_cast<const float4*>(ga + 4);
    }
  };
  auto writeA = [&](int bi) {  // cvt + LDS write (regs loaded an iter ago)
    #pragma unroll
    for (int i = 0; i < 2; ++i) {
      int p = t + (i << 8);
      struct alignas(16) { unsigned short u[8]; } pk;
      pk.u[0] = f2bf_bits(ra[i].x); pk.u[1] = f2bf_bits(ra[i].y);
      pk.u[2] = f2bf_bits(ra[i].z); pk.u[3] = f2bf_bits(ra[i].w);
      pk.u[4] = f2bf_bits(rb[i].x); pk.u[5] = f2bf_bits(rb[i].y);
      pk.u[6] = f2bf_bits(rb[i].z); pk.u[7] = f2bf_bits(rb[i].w);
      *reinterpret_cast<int4*>((char*)&Al[bi][0] + p * 16) =
          *reinterpret_cast<const int4*>(pk.u);
    }
  };
  auto loadB = [&](int ks, int bi) {   // 256 rows x 64 B = 4 chunks/thread
    #pragma unroll
    for (int i = 0; i < 4; ++i) {
      int p = t + (i << 8);
      int r = p >> 2, c = p & 3;
      int f = (r + (r >> 2)) & 3;
      gload_lds16((const char*)WT + (size_t)(n0 + r) * 2048 + (ks << 6) + ((c ^ f) << 4),
                  (char*)&Bl[bi][0] + p * 16);
    }
  };

  floatx4 acc[4][8] = {};
  loadB(0, 0);
  loadA(0);
  writeA(0);        // tile 0 into buf0 (latency exposed once, prologue only)
  loadA(1);         // in flight across the first barrier

  for (int ks = 0; ks < 32; ++ks) {
    __syncthreads();
    const int bi = ks & 1;
    if (ks + 1 < 32) {
      loadB(ks + 1, bi ^ 1);   // async direct-to-LDS
      writeA(bi ^ 1);          // tile ks+1: regs issued at iter ks-1
    }
    if (ks + 2 < 32) loadA(ks + 2);  // issue-early for next writeA

    bf16x8 af[4], bfr[8];
    #pragma unroll
    for (int mb = 0; mb < 4; ++mb) {
      int m = wm + mb * 16 + ln;
      int fm = (m + (m >> 2)) & 3;
      af[mb] = *reinterpret_cast<const bf16x8*>(&Al[bi][m * 32 + ((qd ^ fm) << 3)]);
    }
    #pragma unroll
    for (int nb = 0; nb < 8; ++nb) {
      int n = wn + nb * 16 + ln;
      int fn = (n + (n >> 2)) & 3;
      bfr[nb] = *reinterpret_cast<const bf16x8*>(&Bl[bi][n * 32 + ((qd ^ fn) << 3)]);
    }
    #pragma unroll
    for (int mb = 0; mb < 4; ++mb)
      #pragma unroll
      for (int nb = 0; nb < 8; ++nb)
        acc[mb][nb] = __builtin_amdgcn_mfma_f32_16x16x32_bf16(af[mb], bfr[nb], acc[mb][nb], 0, 0, 0);
  }

  if (blockIdx.z != 2) {
    unsigned short* Y = blockIdx.z == 0 ? qw : kw;
    #pragma unroll
    for (int mb = 0; mb < 4; ++mb)
      #pragma unroll
      for (int nb = 0; nb < 8; ++nb)
        #pragma unroll
        for (int i = 0; i < 4; ++i) {
          int m = m0 + wm + mb * 16 + qd * 4 + i;
          int n = n0 + wn + nb * 16 + ln;
          Y[(size_t)m * NPROJ + n] = f2bf_bits(acc[mb][nb][i]);
        }
  } else {
    // vt[(b*16 + n>>6)*64 + (n&63)][s], s = m & 2047; whole block is one b.
    const int b = m0 >> 11;
    const int sbase = (m0 & 2047) + wm + qd * 4;
    #pragma unroll
    for (int mb = 0; mb < 4; ++mb) {
      int mloc = wm + mb * 16 + qd * 4;        // local row in [0,128)
      int s = sbase + mb * 16;
      #pragma unroll
      for (int nb = 0; nb < 8; ++nb) {
        int n = n0 + wn + nb * 16 + ln;
        size_t row = (size_t)(b * 16 + (n >> 6)) * 64 + (n & 63);
        ushort4 o;
        o.x = vml[mloc + 0] ? f2bf_bits(acc[mb][nb][0]) : (unsigned short)0;
        o.y = vml[mloc + 1] ? f2bf_bits(acc[mb][nb][1]) : (unsigned short)0;
        o.z = vml[mloc + 2] ? f2bf_bits(acc[mb][nb][2]) : (unsigned short)0;
        o.w = vml[mloc + 3] ? f2bf_bits(acc[mb][nb][3]) : (unsigned short)0;
        *reinterpret_cast<ushort4*>(&vt[row * SEQ + s]) = o;
      }
    }
  }
}

// ---------------------------------------------------------------------------
// Kernel 4: flash attention. grid (bh=32, q-tiles=8 of 256 rows), 512 thr.
// 8 waves: qh = wid>>1 (owns 64 q-rows as 2 sub-blocks of 32), kh = wid&1
// (keys kh*32..+31 per 64-key tile). A-reuse: each kf/v/mf LDS read feeds
// both q-sub-blocks. Swapped QK^T: s = mfma(K_rows, Q); sigma-permuted K
// staging (swap bits 2<->3) => lane holds keys kh*32+16kk+8hi+{0..7};
// scalar RNE pack. Max-free softmax => key-half partials merge by ADDITION
// via LDS epilogue. Dynamic LDS 67,584 B (epilogue 256x66 f32 merge buffer
// reuses the K/V area), 1 block/CU (grid = 256 = #CUs).
// ---------------------------------------------------------------------------
__global__ __launch_bounds__(512, 2) void attn_fwd(
    const unsigned short* __restrict__ qw, const unsigned short* __restrict__ kw,
    const unsigned short* __restrict__ vt, const unsigned short* __restrict__ mb,
    float* __restrict__ out)
{
  extern __shared__ char smem[];
  unsigned short* Kl = (unsigned short*)smem;             // 2 * 64*64 bf16 = 16384 B
  unsigned short* Vl = (unsigned short*)(smem + 16384);   // 16384 B
  unsigned short* Ml = (unsigned short*)(smem + 32768);   // 2 * 64 bf16 = 256 B

  const int t = threadIdx.x, lane = t & 63, wid = t >> 6;
  const int l5 = lane & 31, hi = lane >> 5;
  const int qh = wid >> 1, kh = wid & 1;
  const int bh = blockIdx.x;
  const int q0 = blockIdx.y * 256;
  const int b = bh >> 4, h = bh & 15;
  const int base = b * SEQ;

  auto stage = [&](int kt, int bi) {
    const int k0 = kt << 6;
    int rb = wid * 8;                 // 8 rows per wave, 8 waves = 64 rows
    int r = rb + (lane >> 3);
    // sigma(r): swap bit2<->bit3 (verified R6) — QK^T D-row crow then maps
    // to actual key 16*(crow>>3)+8hi+(crow&7) (PV-native order).
    int rsrc = (r & ~12) | ((r & 4) << 1) | ((r & 8) >> 1);
    int sw = ((lane & 7) ^ (r & 7)) << 4;
    gload_lds16((const char*)kw + ((size_t)((base + k0 + rsrc) * NPROJ + h * 64) << 1) + sw,
                (char*)&Kl[bi * 4096] + rb * 128);
    gload_lds16((const char*)vt + ((size_t)((bh * 64 + r) * SEQ + k0) << 1) + sw,
                (char*)&Vl[bi * 4096] + rb * 128);
    if (wid == 7 && lane < 8)
      gload_lds16((const char*)mb + ((size_t)(base + k0 + lane * 8) << 1), (char*)&Ml[bi * 64]);
  };

  // Q fragments straight from global: two 32-row sub-blocks per wave.
  bf16x8 qfa[4], qfb[4];
  {
    const unsigned short* qpa =
        qw + (size_t)(base + q0 + qh * 64 + l5) * NPROJ + h * 64 + hi * 8;
    const unsigned short* qpb = qpa + (size_t)32 * NPROJ;
    #pragma unroll
    for (int kk = 0; kk < 4; ++kk) {
      qfa[kk] = *reinterpret_cast<const bf16x8*>(qpa + kk * 16);
      qfb[kk] = *reinterpret_cast<const bf16x8*>(qpb + kk * 16);
    }
  }

  floatx16 oa0a = {}, oa1a = {}, laa = {};
  floatx16 oa0b = {}, oa1b = {}, lab = {};
  stage(0, 0);

  #pragma unroll 2
  for (int kt = 0; kt < SEQ / 64; ++kt) {
    __syncthreads();
    if (kt + 1 < SEQ / 64) stage(kt + 1, (kt + 1) & 1);
    const int bi = kt & 1;

    // QK^T: A = permuted K rows (kh half), read ONCE, used for both q-blocks.
    floatx16 sa = {}, sb = {};
    __builtin_amdgcn_s_setprio(1);
    #pragma unroll
    for (int kk = 0; kk < 4; ++kk) {
      int ph = ((kk * 2 + hi) ^ (l5 & 7)) << 3;
      bf16x8 kf = *reinterpret_cast<const bf16x8*>(&Kl[bi * 4096 + (kh * 32 + l5) * 64 + ph]);
      sa = __builtin_amdgcn_mfma_f32_32x32x16_bf16(kf, qfa[kk], sa, 0, 0, 0);
      sb = __builtin_amdgcn_mfma_f32_32x32x16_bf16(kf, qfb[kk], sb, 0, 0, 0);
    }
    __builtin_amdgcn_s_setprio(0);

    // exp2 in-register. s[r] = key kh*32 + 16*(r>>3) + 8hi + (r&7).
    float pea[16], peb[16];
    #pragma unroll
    for (int r = 0; r < 16; ++r) {
      pea[r] = __builtin_amdgcn_exp2f(sa[r]);
      peb[r] = __builtin_amdgcn_exp2f(sb[r]);
    }

    #pragma unroll
    for (int kk = 0; kk < 2; ++kk) {
      struct alignas(16) { unsigned short u[8]; } pka, pkb;
      #pragma unroll
      for (int j = 0; j < 8; ++j) {
        pka.u[j] = f2bf_bits(pea[8 * kk + j]);
        pkb.u[j] = f2bf_bits(peb[8 * kk + j]);
      }
      bf16x8 paa = __builtin_bit_cast(bf16x8, pka);
      bf16x8 pab = __builtin_bit_cast(bf16x8, pkb);
      int ch = ((4 * kh + 2 * kk + hi) ^ (l5 & 7)) << 3;
      bf16x8 v0 = *reinterpret_cast<const bf16x8*>(&Vl[bi * 4096 + l5 * 64 + ch]);
      bf16x8 v1 = *reinterpret_cast<const bf16x8*>(&Vl[bi * 4096 + (32 + l5) * 64 + ch]);
      bf16x8 mf = *reinterpret_cast<const bf16x8*>(&Ml[bi * 64 + kh * 32 + kk * 16 + hi * 8]);
      __builtin_amdgcn_s_setprio(1);
      oa0a = __builtin_amdgcn_mfma_f32_32x32x16_bf16(paa, v0, oa0a, 0, 0, 0);
      oa1a = __builtin_amdgcn_mfma_f32_32x32x16_bf16(paa, v1, oa1a, 0, 0, 0);
      laa  = __builtin_amdgcn_mfma_f32_32x32x16_bf16(paa, mf, laa, 0, 0, 0);
      oa0b = __builtin_amdgcn_mfma_f32_32x32x16_bf16(pab, v0, oa0b, 0, 0, 0);
      oa1b = __builtin_amdgcn_mfma_f32_32x32x16_bf16(pab, v1, oa1b, 0, 0, 0);
      lab  = __builtin_amdgcn_mfma_f32_32x32x16_bf16(pab, mf, lab, 0, 0, 0);
      __builtin_amdgcn_s_setprio(0);
    }
  }

  // Merge the two key-half partials (plain addition — max-free softmax).
  __syncthreads();
  float* Mg = (float*)smem;           // 256 rows x 66 fp32 = 67,584 B
  if (kh == 1) {
    #pragma unroll
    for (int r = 0; r < 16; ++r) {
      int m = (r & 3) + ((r >> 2) << 3) + (hi << 2);
      int rowa = qh * 64 + m, rowb = qh * 64 + 32 + m;
      Mg[rowa * 66 + l5] = oa0a[r];
      Mg[rowa * 66 + 32 + l5] = oa1a[r];
      Mg[rowb * 66 + l5] = oa0b[r];
      Mg[rowb * 66 + 32 + l5] = oa1b[r];
      if (l5 == 0) { Mg[rowa * 66 + 64] = laa[r]; Mg[rowb * 66 + 64] = lab[r]; }
    }
  }
  __syncthreads();
  if (kh == 0) {
    #pragma unroll
    for (int r = 0; r < 16; ++r) {
      int m = (r & 3) + ((r >> 2) << 3) + (hi << 2);
      int rowa = qh * 64 + m, rowb = qh * 64 + 32 + m;
      float o0a = oa0a[r] + Mg[rowa * 66 + l5];
      float o1a = oa1a[r] + Mg[rowa * 66 + 32 + l5];
      float inva = 1.0f / (laa[r] + Mg[rowa * 66 + 64]);
      size_t oa_ = (size_t)(base + q0 + rowa) * NPROJ + h * 64;
      out[oa_ + l5] = o0a * inva;
      out[oa_ + 32 + l5] = o1a * inva;
      float o0b = oa0b[r] + Mg[rowb * 66 + l5];
      float o1b = oa1b[r] + Mg[rowb * 66 + 32 + l5];
      float invb = 1.0f / (lab[r] + Mg[rowb * 66 + 64]);
      size_t ob_ = (size_t)(base + q0 + rowb) * NPROJ + h * 64;
      out[ob_ + l5] = o0b * invb;
      out[ob_ + 32 + l5] = o1b * invb;
    }
  }
}

// ---------------------------------------------------------------------------
extern "C" void kernel_launch(void* const* d_in, const int* in_sizes, int n_in,
                              void* d_out, int out_size, void* d_ws, size_t ws_size,
                              hipStream_t stream) {
  const float* q  = (const float*)d_in[0];
  const float* k  = (const float*)d_in[1];
  const float* v  = (const float*)d_in[2];
  const int* vm   = (const int*)d_in[3];
  const float* Wq = (const float*)d_in[4];
  const float* Wk = (const float*)d_in[5];
  const float* Wv = (const float*)d_in[6];
  float* out = (float*)d_out;

  unsigned short* ws = (unsigned short*)d_ws;
  unsigned short* WqT = ws + ((size_t)0 << 20);   // 2 MB each
  unsigned short* WkT = ws + ((size_t)1 << 20);
  unsigned short* WvT = ws + ((size_t)2 << 20);
  unsigned short* qw  = ws + ((size_t)3 << 20);   // 8 MB each
  unsigned short* kw  = ws + ((size_t)7 << 20);
  unsigned short* mbv = ws + ((size_t)11 << 20);  // mask vector
  unsigned short* vt  = ws + ((size_t)15 << 20);  // 16 MB

  transpose_w<<<dim3(16, 16, 3), 256, 0, stream>>>(Wq, Wk, Wv, vm, WqT, WkT, WvT, mbv);
  proj_gemm<<<dim3(32, 4, 3), 256, 0, stream>>>(q, k, v, WqT, WkT, WvT, vm, qw, kw, vt);
  attn_fwd<<<dim3(32, 8), 512, 67584, stream>>>(qw, kw, vt, mbv, out);
}

// Round 24
// 91.146 us; speedup vs baseline: 1.4272x; 1.4272x over previous
//
#include <hip/hip_runtime.h>
#include <hip/hip_bf16.h>

// MultiHeadAttention: B=2, S=2048, D=1024, H=16, key=head=64
// R15/R18/R22 hardware-verified best configuration (91.2 us, triple-confirmed).
// R23 falsified the 128x256 proj tile at (256,3): acc[4][8] needs 128 VGPR,
// the 3-wave cap forced spills (VGPR 104->84, MfmaUtil 8%, 130 us). Tile
// family closed on both occupancy settings; reverting to verified best.
// transpose_w (W->W^T bf16, Wq pre-scaled 0.125*log2e; also emits mb bf16 mask)
// proj_gemm (128x128, fused fp32->bf16 A-staging, T14 issue-early/write-late;
//   z==2 epilogue writes vt[b][h][d][s] directly with mask-zeroing)
// attn_fwd (Q-tile 256, 8 waves qh x kh, A-reuse, swapped QK^T,
//   sigma-permuted K staging, in-register P, merge-by-addition epilogue)

#define SEQ 2048
#define DIM 1024
#define NPROJ 1024

typedef __bf16 bf16x8 __attribute__((ext_vector_type(8)));
typedef float floatx4 __attribute__((ext_vector_type(4)));
typedef float floatx16 __attribute__((ext_vector_type(16)));

__device__ inline unsigned short f2bf_bits(float x) {
  __hip_bfloat16 h = __float2bfloat16(x);
  return __builtin_bit_cast(unsigned short, h);
}

__device__ __forceinline__ void gload_lds16(const void* g, void* l) {
  __builtin_amdgcn_global_load_lds((const __attribute__((address_space(1))) void*)g,
                                   (__attribute__((address_space(3))) void*)l, 16, 0, 0);
}

// ---------------------------------------------------------------------------
// Kernel 1: W [1024x1024] fp32 -> W^T bf16; Wq scaled by 0.125*log2e.
// Side job (z==1, y==0, x<16): mb[b][s] = bf16(mask) for attn's rowsum MFMA.
// ---------------------------------------------------------------------------
__global__ __launch_bounds__(256) void transpose_w(
    const float* __restrict__ Wq, const float* __restrict__ Wk, const float* __restrict__ Wv,
    const int* __restrict__ vmask,
    unsigned short* __restrict__ WqT, unsigned short* __restrict__ WkT, unsigned short* __restrict__ WvT,
    unsigned short* __restrict__ mb)
{
  if (blockIdx.z == 1 && blockIdx.y == 0 && blockIdx.x < 16) {
    int i = blockIdx.x * 256 + threadIdx.x;
    mb[i] = vmask[i] ? 0x3F80 : 0;   // bf16 1.0 or 0.0
  }
  const float* W = blockIdx.z == 0 ? Wq : (blockIdx.z == 1 ? Wk : Wv);
  unsigned short* WT = blockIdx.z == 0 ? WqT : (blockIdx.z == 1 ? WkT : WvT);
  const float sc = (blockIdx.z == 0) ? 0.1803368801f : 1.0f;
  __shared__ float tile[64][65];
  const int k0 = blockIdx.x * 64;
  const int n0 = blockIdx.y * 64;
  const int t = threadIdx.x;
  #pragma unroll
  for (int it = 0; it < 4; ++it) {
    int idx = t + (it << 8);
    int r = idx >> 4, c4 = (idx & 15) << 2;
    float4 v = *reinterpret_cast<const float4*>(&W[(k0 + r) * DIM + n0 + c4]);
    tile[r][c4 + 0] = v.x; tile[r][c4 + 1] = v.y;
    tile[r][c4 + 2] = v.z; tile[r][c4 + 3] = v.w;
  }
  __syncthreads();
  #pragma unroll
  for (int it = 0; it < 4; ++it) {
    int idx = t + (it << 8);
    int r = idx >> 4, c4 = (idx & 15) << 2;
    ushort4 o;
    o.x = f2bf_bits(tile[c4 + 0][r] * sc);
    o.y = f2bf_bits(tile[c4 + 1][r] * sc);
    o.z = f2bf_bits(tile[c4 + 2][r] * sc);
    o.w = f2bf_bits(tile[c4 + 3][r] * sc);
    *reinterpret_cast<ushort4*>(&WT[(n0 + r) * DIM + k0 + c4]) = o;
  }
}

// ---------------------------------------------------------------------------
// Kernel 2: Y = bf16( X @ W ), X = q/k/v fp32 [4096x1024] read DIRECTLY.
// T14 split A-staging (issue-early / write-late), B via global_load_lds.
// z==0/1: Y = qw/kw row-major. z==2: epilogue writes vt[(b16+h)64+d][s]
// directly (mask-zeroed rows via LDS-staged vmask slice) — one aligned
// ushort4 store per acc group; vw intermediate eliminated.
// 128x128 tile, BK=32, double-buffered, 32 KB LDS (+512 B mask slice).
// ---------------------------------------------------------------------------
__global__ __launch_bounds__(256, 4) void proj_gemm(
    const float* __restrict__ xq, const float* __restrict__ xk, const float* __restrict__ xv,
    const unsigned short* __restrict__ WqT, const unsigned short* __restrict__ WkT,
    const unsigned short* __restrict__ WvT, const int* __restrict__ vmask,
    unsigned short* __restrict__ qw, unsigned short* __restrict__ kw, unsigned short* __restrict__ vt)
{
  const float* X = blockIdx.z == 0 ? xq : (blockIdx.z == 1 ? xk : xv);
  const unsigned short* WT = blockIdx.z == 0 ? WqT : (blockIdx.z == 1 ? WkT : WvT);

  __shared__ unsigned short Al[2][128 * 32];  // [m][k] bf16, 64B rows, swizzled chunks
  __shared__ unsigned short Bl[2][128 * 32];  // [n][k]
  __shared__ int vml[128];                    // z==2: mask slice for rows m0..m0+127

  const int m0 = blockIdx.x * 128, n0 = blockIdx.y * 128;
  const int t = threadIdx.x;
  const int lane = t & 63;
  const int wid = t >> 6;
  const int wm = (wid >> 1) << 6, wn = (wid & 1) << 6;
  const int qd = lane >> 4, ln = lane & 15;

  if (blockIdx.z == 2 && t < 128) vml[t] = vmask[m0 + t];

  float4 ra[2], rb[2];   // in-flight A chunks (one tile resident at a time)

  auto loadA = [&](int ks) {   // issue only — no wait
    #pragma unroll
    for (int i = 0; i < 2; ++i) {
      int p = t + (i << 8);
      int r = p >> 2, c = p & 3;
      int f = (r + (r >> 2)) & 3;
      const float* ga = X + (size_t)(m0 + r) * 1024 + ks * 32 + ((c ^ f) << 3);
      ra[i] = *reinterpret_cast<const float4*>(ga);
      rb[i] = *reinterpret_cast<const float4*>(ga + 4);
    }
  };
  auto writeA = [&](int bi) {  // cvt + LDS write (regs loaded an iter ago)
    #pragma unroll
    for (int i = 0; i < 2; ++i) {
      int p = t + (i << 8);
      struct alignas(16) { unsigned short u[8]; } pk;
      pk.u[0] = f2bf_bits(ra[i].x); pk.u[1] = f2bf_bits(ra[i].y);
      pk.u[2] = f2bf_bits(ra[i].z); pk.u[3] = f2bf_bits(ra[i].w);
      pk.u[4] = f2bf_bits(rb[i].x); pk.u[5] = f2bf_bits(rb[i].y);
      pk.u[6] = f2bf_bits(rb[i].z); pk.u[7] = f2bf_bits(rb[i].w);
      *reinterpret_cast<int4*>((char*)&Al[bi][0] + p * 16) =
          *reinterpret_cast<const int4*>(pk.u);
    }
  };
  auto loadB = [&](int ks, int bi) {
    #pragma unroll
    for (int i = 0; i < 2; ++i) {
      int p = t + (i << 8);
      int r = p >> 2, c = p & 3;
      int f = (r + (r >> 2)) & 3;
      gload_lds16((const char*)WT + (size_t)(n0 + r) * 2048 + (ks << 6) + ((c ^ f) << 4),
                  (char*)&Bl[bi][0] + p * 16);
    }
  };

  floatx4 acc[4][4] = {};
  loadB(0, 0);
  loadA(0);
  writeA(0);        // tile 0 into buf0 (latency exposed once, prologue only)
  loadA(1);         // in flight across the first barrier

  for (int ks = 0; ks < 32; ++ks) {
    __syncthreads();
    const int bi = ks & 1;
    if (ks + 1 < 32) {
      loadB(ks + 1, bi ^ 1);   // async direct-to-LDS
      writeA(bi ^ 1);          // tile ks+1: regs issued at iter ks-1
    }
    if (ks + 2 < 32) loadA(ks + 2);  // issue-early for next writeA

    bf16x8 af[4], bfr[4];
    #pragma unroll
    for (int mb = 0; mb < 4; ++mb) {
      int m = wm + mb * 16 + ln;
      int fm = (m + (m >> 2)) & 3;
      af[mb] = *reinterpret_cast<const bf16x8*>(&Al[bi][m * 32 + ((qd ^ fm) << 3)]);
    }
    #pragma unroll
    for (int nb = 0; nb < 4; ++nb) {
      int n = wn + nb * 16 + ln;
      int fn = (n + (n >> 2)) & 3;
      bfr[nb] = *reinterpret_cast<const bf16x8*>(&Bl[bi][n * 32 + ((qd ^ fn) << 3)]);
    }
    #pragma unroll
    for (int mb = 0; mb < 4; ++mb)
      #pragma unroll
      for (int nb = 0; nb < 4; ++nb)
        acc[mb][nb] = __builtin_amdgcn_mfma_f32_16x16x32_bf16(af[mb], bfr[nb], acc[mb][nb], 0, 0, 0);
  }

  if (blockIdx.z != 2) {
    unsigned short* Y = blockIdx.z == 0 ? qw : kw;
    #pragma unroll
    for (int mb = 0; mb < 4; ++mb)
      #pragma unroll
      for (int nb = 0; nb < 4; ++nb)
        #pragma unroll
        for (int i = 0; i < 4; ++i) {
          int m = m0 + wm + mb * 16 + qd * 4 + i;
          int n = n0 + wn + nb * 16 + ln;
          Y[(size_t)m * NPROJ + n] = f2bf_bits(acc[mb][nb][i]);
        }
  } else {
    // vt[(b*16 + n>>6)*64 + (n&63)][s], s = m & 2047; whole block is one b.
    const int b = m0 >> 11;
    const int sbase = (m0 & 2047) + wm + qd * 4;
    #pragma unroll
    for (int mb = 0; mb < 4; ++mb) {
      int mloc = wm + mb * 16 + qd * 4;        // local row in [0,128)
      int s = sbase + mb * 16;
      #pragma unroll
      for (int nb = 0; nb < 4; ++nb) {
        int n = n0 + wn + nb * 16 + ln;
        size_t row = (size_t)(b * 16 + (n >> 6)) * 64 + (n & 63);
        ushort4 o;
        o.x = vml[mloc + 0] ? f2bf_bits(acc[mb][nb][0]) : (unsigned short)0;
        o.y = vml[mloc + 1] ? f2bf_bits(acc[mb][nb][1]) : (unsigned short)0;
        o.z = vml[mloc + 2] ? f2bf_bits(acc[mb][nb][2]) : (unsigned short)0;
        o.w = vml[mloc + 3] ? f2bf_bits(acc[mb][nb][3]) : (unsigned short)0;
        *reinterpret_cast<ushort4*>(&vt[row * SEQ + s]) = o;
      }
    }
  }
}

// ---------------------------------------------------------------------------
// Kernel 4: flash attention. grid (bh=32, q-tiles=8 of 256 rows), 512 thr.
// 8 waves: qh = wid>>1 (owns 64 q-rows as 2 sub-blocks of 32), kh = wid&1
// (keys kh*32..+31 per 64-key tile). A-reuse: each kf/v/mf LDS read feeds
// both q-sub-blocks. Swapped QK^T: s = mfma(K_rows, Q); sigma-permuted K
// staging (swap bits 2<->3) => lane holds keys kh*32+16kk+8hi+{0..7};
// scalar RNE pack. Max-free softmax => key-half partials merge by ADDITION
// via LDS epilogue. Dynamic LDS 67,584 B (epilogue 256x66 f32 merge buffer
// reuses the K/V area), 1 block/CU (grid = 256 = #CUs).
// ---------------------------------------------------------------------------
__global__ __launch_bounds__(512, 2) void attn_fwd(
    const unsigned short* __restrict__ qw, const unsigned short* __restrict__ kw,
    const unsigned short* __restrict__ vt, const unsigned short* __restrict__ mb,
    float* __restrict__ out)
{
  extern __shared__ char smem[];
  unsigned short* Kl = (unsigned short*)smem;             // 2 * 64*64 bf16 = 16384 B
  unsigned short* Vl = (unsigned short*)(smem + 16384);   // 16384 B
  unsigned short* Ml = (unsigned short*)(smem + 32768);   // 2 * 64 bf16 = 256 B

  const int t = threadIdx.x, lane = t & 63, wid = t >> 6;
  const int l5 = lane & 31, hi = lane >> 5;
  const int qh = wid >> 1, kh = wid & 1;
  const int bh = blockIdx.x;
  const int q0 = blockIdx.y * 256;
  const int b = bh >> 4, h = bh & 15;
  const int base = b * SEQ;

  auto stage = [&](int kt, int bi) {
    const int k0 = kt << 6;
    int rb = wid * 8;                 // 8 rows per wave, 8 waves = 64 rows
    int r = rb + (lane >> 3);
    // sigma(r): swap bit2<->bit3 (verified R6) — QK^T D-row crow then maps
    // to actual key 16*(crow>>3)+8hi+(crow&7) (PV-native order).
    int rsrc = (r & ~12) | ((r & 4) << 1) | ((r & 8) >> 1);
    int sw = ((lane & 7) ^ (r & 7)) << 4;
    gload_lds16((const char*)kw + ((size_t)((base + k0 + rsrc) * NPROJ + h * 64) << 1) + sw,
                (char*)&Kl[bi * 4096] + rb * 128);
    gload_lds16((const char*)vt + ((size_t)((bh * 64 + r) * SEQ + k0) << 1) + sw,
                (char*)&Vl[bi * 4096] + rb * 128);
    if (wid == 7 && lane < 8)
      gload_lds16((const char*)mb + ((size_t)(base + k0 + lane * 8) << 1), (char*)&Ml[bi * 64]);
  };

  // Q fragments straight from global: two 32-row sub-blocks per wave.
  bf16x8 qfa[4], qfb[4];
  {
    const unsigned short* qpa =
        qw + (size_t)(base + q0 + qh * 64 + l5) * NPROJ + h * 64 + hi * 8;
    const unsigned short* qpb = qpa + (size_t)32 * NPROJ;
    #pragma unroll
    for (int kk = 0; kk < 4; ++kk) {
      qfa[kk] = *reinterpret_cast<const bf16x8*>(qpa + kk * 16);
      qfb[kk] = *reinterpret_cast<const bf16x8*>(qpb + kk * 16);
    }
  }

  floatx16 oa0a = {}, oa1a = {}, laa = {};
  floatx16 oa0b = {}, oa1b = {}, lab = {};
  stage(0, 0);

  #pragma unroll 2
  for (int kt = 0; kt < SEQ / 64; ++kt) {
    __syncthreads();
    if (kt + 1 < SEQ / 64) stage(kt + 1, (kt + 1) & 1);
    const int bi = kt & 1;

    // QK^T: A = permuted K rows (kh half), read ONCE, used for both q-blocks.
    floatx16 sa = {}, sb = {};
    __builtin_amdgcn_s_setprio(1);
    #pragma unroll
    for (int kk = 0; kk < 4; ++kk) {
      int ph = ((kk * 2 + hi) ^ (l5 & 7)) << 3;
      bf16x8 kf = *reinterpret_cast<const bf16x8*>(&Kl[bi * 4096 + (kh * 32 + l5) * 64 + ph]);
      sa = __builtin_amdgcn_mfma_f32_32x32x16_bf16(kf, qfa[kk], sa, 0, 0, 0);
      sb = __builtin_amdgcn_mfma_f32_32x32x16_bf16(kf, qfb[kk], sb, 0, 0, 0);
    }
    __builtin_amdgcn_s_setprio(0);

    // exp2 in-register. s[r] = key kh*32 + 16*(r>>3) + 8hi + (r&7).
    float pea[16], peb[16];
    #pragma unroll
    for (int r = 0; r < 16; ++r) {
      pea[r] = __builtin_amdgcn_exp2f(sa[r]);
      peb[r] = __builtin_amdgcn_exp2f(sb[r]);
    }

    #pragma unroll
    for (int kk = 0; kk < 2; ++kk) {
      struct alignas(16) { unsigned short u[8]; } pka, pkb;
      #pragma unroll
      for (int j = 0; j < 8; ++j) {
        pka.u[j] = f2bf_bits(pea[8 * kk + j]);
        pkb.u[j] = f2bf_bits(peb[8 * kk + j]);
      }
      bf16x8 paa = __builtin_bit_cast(bf16x8, pka);
      bf16x8 pab = __builtin_bit_cast(bf16x8, pkb);
      int ch = ((4 * kh + 2 * kk + hi) ^ (l5 & 7)) << 3;
      bf16x8 v0 = *reinterpret_cast<const bf16x8*>(&Vl[bi * 4096 + l5 * 64 + ch]);
      bf16x8 v1 = *reinterpret_cast<const bf16x8*>(&Vl[bi * 4096 + (32 + l5) * 64 + ch]);
      bf16x8 mf = *reinterpret_cast<const bf16x8*>(&Ml[bi * 64 + kh * 32 + kk * 16 + hi * 8]);
      __builtin_amdgcn_s_setprio(1);
      oa0a = __builtin_amdgcn_mfma_f32_32x32x16_bf16(paa, v0, oa0a, 0, 0, 0);
      oa1a = __builtin_amdgcn_mfma_f32_32x32x16_bf16(paa, v1, oa1a, 0, 0, 0);
      laa  = __builtin_amdgcn_mfma_f32_32x32x16_bf16(paa, mf, laa, 0, 0, 0);
      oa0b = __builtin_amdgcn_mfma_f32_32x32x16_bf16(pab, v0, oa0b, 0, 0, 0);
      oa1b = __builtin_amdgcn_mfma_f32_32x32x16_bf16(pab, v1, oa1b, 0, 0, 0);
      lab  = __builtin_amdgcn_mfma_f32_32x32x16_bf16(pab, mf, lab, 0, 0, 0);
      __builtin_amdgcn_s_setprio(0);
    }
  }

  // Merge the two key-half partials (plain addition — max-free softmax).
  __syncthreads();
  float* Mg = (float*)smem;           // 256 rows x 66 fp32 = 67,584 B
  if (kh == 1) {
    #pragma unroll
    for (int r = 0; r < 16; ++r) {
      int m = (r & 3) + ((r >> 2) << 3) + (hi << 2);
      int rowa = qh * 64 + m, rowb = qh * 64 + 32 + m;
      Mg[rowa * 66 + l5] = oa0a[r];
      Mg[rowa * 66 + 32 + l5] = oa1a[r];
      Mg[rowb * 66 + l5] = oa0b[r];
      Mg[rowb * 66 + 32 + l5] = oa1b[r];
      if (l5 == 0) { Mg[rowa * 66 + 64] = laa[r]; Mg[rowb * 66 + 64] = lab[r]; }
    }
  }
  __syncthreads();
  if (kh == 0) {
    #pragma unroll
    for (int r = 0; r < 16; ++r) {
      int m = (r & 3) + ((r >> 2) << 3) + (hi << 2);
      int rowa = qh * 64 + m, rowb = qh * 64 + 32 + m;
      float o0a = oa0a[r] + Mg[rowa * 66 + l5];
      float o1a = oa1a[r] + Mg[rowa * 66 + 32 + l5];
      float inva = 1.0f / (laa[r] + Mg[rowa * 66 + 64]);
      size_t oa_ = (size_t)(base + q0 + rowa) * NPROJ + h * 64;
      out[oa_ + l5] = o0a * inva;
      out[oa_ + 32 + l5] = o1a * inva;
      float o0b = oa0b[r] + Mg[rowb * 66 + l5];
      float o1b = oa1b[r] + Mg[rowb * 66 + 32 + l5];
      float invb = 1.0f / (lab[r] + Mg[rowb * 66 + 64]);
      size_t ob_ = (size_t)(base + q0 + rowb) * NPROJ + h * 64;
      out[ob_ + l5] = o0b * invb;
      out[ob_ + 32 + l5] = o1b * invb;
    }
  }
}

// ---------------------------------------------------------------------------
extern "C" void kernel_launch(void* const* d_in, const int* in_sizes, int n_in,
                              void* d_out, int out_size, void* d_ws, size_t ws_size,
                              hipStream_t stream) {
  const float* q  = (const float*)d_in[0];
  const float* k  = (const float*)d_in[1];
  const float* v  = (const float*)d_in[2];
  const int* vm   = (const int*)d_in[3];
  const float* Wq = (const float*)d_in[4];
  const float* Wk = (const float*)d_in[5];
  const float* Wv = (const float*)d_in[6];
  float* out = (float*)d_out;

  unsigned short* ws = (unsigned short*)d_ws;
  unsigned short* WqT = ws + ((size_t)0 << 20);   // 2 MB each
  unsigned short* WkT = ws + ((size_t)1 << 20);
  unsigned short* WvT = ws + ((size_t)2 << 20);
  unsigned short* qw  = ws + ((size_t)3 << 20);   // 8 MB each
  unsigned short* kw  = ws + ((size_t)7 << 20);
  unsigned short* mbv = ws + ((size_t)11 << 20);  // mask vector
  unsigned short* vt  = ws + ((size_t)15 << 20);  // 16 MB

  transpose_w<<<dim3(16, 16, 3), 256, 0, stream>>>(Wq, Wk, Wv, vm, WqT, WkT, WvT, mbv);
  proj_gemm<<<dim3(32, 8, 3), 256, 0, stream>>>(q, k, v, WqT, WkT, WvT, vm, qw, kw, vt);
  attn_fwd<<<dim3(32, 8), 512, 67584, stream>>>(qw, kw, vt, mbv, out);
}